// Round 13
// baseline (562.271 us; speedup 1.0000x reference)
//
#include <hip/hip_runtime.h>

#define N_NODES 50000
#define N_EDGES 600000
#define DFEAT   128
#define SCAN_NB 196                      // scan tiles: 196 blocks of 256 counts
#define CSR_NB  1024                     // csr kernel grid (co-resident: 4096 waves)

typedef __attribute__((ext_vector_type(8))) short short8;
typedef __attribute__((ext_vector_type(4))) float floatx4;

__device__ __forceinline__ unsigned short f2bf_rtne(float f) {
    unsigned b = __float_as_uint(f);
    return (unsigned short)((b + 0x7FFFu + ((b >> 16) & 1u)) >> 16);
}
__device__ __forceinline__ float bf2f(unsigned short u) {
    return __uint_as_float(((unsigned)u) << 16);
}

// ================= prep: zero cnt/ctrs | x->bf16 table | W split/swizzle =========
__global__ __launch_bounds__(256) void sage_prep_kernel(
        const float* __restrict__ x,
        const float* __restrict__ Ws0, const float* __restrict__ Wn0,
        const float* __restrict__ Ws1, const float* __restrict__ Wn1,
        const float* __restrict__ Ws2, const float* __restrict__ Wn2,
        unsigned short* __restrict__ Whi0, unsigned short* __restrict__ Wlo0,
        unsigned short* __restrict__ Whi1, unsigned short* __restrict__ Wlo1,
        unsigned short* __restrict__ Whi2, unsigned short* __restrict__ Wlo2,
        unsigned short* __restrict__ hb, int* __restrict__ cnt,
        unsigned* __restrict__ ctrs)
{
    const int gtid = blockIdx.x * 256 + threadIdx.x;
    const int gsz  = gridDim.x * 256;
    if (gtid < 8) ctrs[gtid] = 0u;
    for (int i = gtid; i < 50176; i += gsz) cnt[i] = 0;
    for (int i = gtid; i < N_NODES * DFEAT / 4; i += gsz) {
        float4 v = ((const float4*)x)[i];
        ushort4 o;
        o.x = f2bf_rtne(v.x); o.y = f2bf_rtne(v.y);
        o.z = f2bf_rtne(v.z); o.w = f2bf_rtne(v.w);
        ((ushort4*)hb)[i] = o;
    }
    for (int it = gtid; it < 160 * 64; it += gsz) {
        int fid_g = it >> 6;
        int lane  = it & 63;
        const float *Ws, *Wn;
        unsigned short *Whi, *Wlo;
        int N, fid;
        if (fid_g < 64)       { Ws = Ws0; Wn = Wn0; Whi = Whi0; Wlo = Wlo0; N = 128; fid = fid_g; }
        else if (fid_g < 128) { Ws = Ws1; Wn = Wn1; Whi = Whi1; Wlo = Wlo1; N = 128; fid = fid_g - 64; }
        else                  { Ws = Ws2; Wn = Wn2; Whi = Whi2; Wlo = Wlo2; N = 64;  fid = fid_g - 128; }
        int NT = N / 16;
        int kt = fid / NT, nt = fid % NT;
        int kbase = kt * 32 + (lane >> 4) * 8;
        int n = nt * 16 + (lane & 15);
        long base = ((long)fid * 64 + lane) * 8;
        #pragma unroll
        for (int j = 0; j < 8; j++) {
            int k = kbase + j;
            float w = (k < 128) ? Ws[k * N + n] : Wn[(k - 128) * N + n];
            unsigned bb = __float_as_uint(w);
            unsigned hib = bb & 0xFFFF0000u;
            float lo = w - __uint_as_float(hib);
            Whi[base + j] = (unsigned short)(bb >> 16);
            Wlo[base + j] = (unsigned short)(__float_as_uint(lo) >> 16);
        }
    }
}

// ================= software barrier for co-resident grid =============
__device__ __forceinline__ void csr_barrier(unsigned* ctr, unsigned* flag, int nb) {
    __syncthreads();
    if (threadIdx.x == 0) {
        __threadfence();
        unsigned old = __hip_atomic_fetch_add(ctr, 1u, __ATOMIC_ACQ_REL,
                                              __HIP_MEMORY_SCOPE_AGENT);
        if (old == (unsigned)(nb - 1)) {
            __hip_atomic_store(flag, 1u, __ATOMIC_RELEASE, __HIP_MEMORY_SCOPE_AGENT);
        } else {
            while (__hip_atomic_load(flag, __ATOMIC_ACQUIRE,
                                     __HIP_MEMORY_SCOPE_AGENT) == 0u)
                __builtin_amdgcn_s_sleep(2);
        }
        __threadfence();
    }
    __syncthreads();
}

// ================= CSR build at FULL width: hist + scan + fill ===========
// 1024 blocks x 256 threads (4096 waves of 8192 capacity -> co-resident; 16
// waves/CU). Hist/fill run at full width (r12's 196-block starvation fixed);
// scan phases gate on b < SCAN_NB with ticket-scan of block totals.
__global__ __launch_bounds__(256) void sage_csr_kernel(
        const int* __restrict__ src, const int* __restrict__ dst,
        int* __restrict__ cnt, int* __restrict__ bsum,
        int* __restrict__ row_ptr, int* __restrict__ cursor,
        float* __restrict__ invdeg, unsigned short* __restrict__ sorted_src,
        unsigned* __restrict__ ctrs)
{
    const int t = threadIdx.x;
    const int b = blockIdx.x;
    const int gtid = b * 256 + t;
    const int gsz  = CSR_NB * 256;

    // ---- phase 0: histogram (cnt zeroed by prep) ----
    for (int e = gtid; e < N_EDGES; e += gsz) atomicAdd(&cnt[dst[e]], 1);
    csr_barrier(&ctrs[0], &ctrs[1], CSR_NB);

    // ---- phase 1 (blocks < SCAN_NB): local scan + ticket-scan + emit ----
    if (b < SCAN_NB) {
        __shared__ int sws[4];
        __shared__ int lastflag;
        int i = b * 256 + t;
        int v = (i < N_NODES) ? cnt[i] : 0;
        int lane = t & 63, wid = t >> 6;
        int incl = v;
        #pragma unroll
        for (int off = 1; off < 64; off <<= 1) {
            int y = __shfl_up(incl, off);
            if (lane >= off) incl += y;
        }
        if (lane == 63) sws[wid] = incl;
        __syncthreads();
        int wpre = 0;
        for (int w = 0; w < wid; w++) wpre += sws[w];
        int lincl = wpre + incl;                     // block-inclusive prefix
        int btot  = sws[0] + sws[1] + sws[2] + sws[3];
        if (t == 0) {
            bsum[b] = btot;
            __threadfence();
            unsigned old = __hip_atomic_fetch_add(&ctrs[2], 1u, __ATOMIC_ACQ_REL,
                                                  __HIP_MEMORY_SCOPE_AGENT);
            lastflag = (old == (unsigned)(SCAN_NB - 1)) ? 1 : 0;
        }
        __syncthreads();
        if (lastflag) {   // last-arriving block exclusive-scans the 196 totals
            __shared__ int sw2[4];
            int v2 = (t < SCAN_NB) ? bsum[t] : 0;
            int incl2 = v2;
            #pragma unroll
            for (int off = 1; off < 64; off <<= 1) {
                int y = __shfl_up(incl2, off);
                if (lane >= off) incl2 += y;
            }
            if (lane == 63) sw2[wid] = incl2;
            __syncthreads();
            int wpre2 = 0;
            for (int w = 0; w < wid; w++) wpre2 += sw2[w];
            if (t < SCAN_NB) bsum[t] = wpre2 + incl2 - v2;   // exclusive
            __syncthreads();
            if (t == 0) {
                __threadfence();
                __hip_atomic_store(&ctrs[3], 1u, __ATOMIC_RELEASE,
                                   __HIP_MEMORY_SCOPE_AGENT);
            }
        } else if (t == 0) {
            while (__hip_atomic_load(&ctrs[3], __ATOMIC_ACQUIRE,
                                     __HIP_MEMORY_SCOPE_AGENT) == 0u)
                __builtin_amdgcn_s_sleep(2);
            __threadfence();
        }
        __syncthreads();
        int excl = bsum[b] + lincl - v;
        if (i < N_NODES) {
            row_ptr[i] = excl;
            cursor[i]  = excl;
            invdeg[i]  = 1.0f / fmaxf((float)v, 1.0f);
        }
        if (i == N_NODES - 1) row_ptr[N_NODES] = excl + v;
    }
    csr_barrier(&ctrs[4], &ctrs[5], CSR_NB);

    // ---- phase 2: fill sorted_src via cursor (full width) ----
    for (int e = gtid; e < N_EDGES; e += gsz) {
        int p = atomicAdd(&cursor[dst[e]], 1);
        sorted_src[p] = (unsigned short)src[e];
    }
}

// ================= gather: paired-edge wave-per-node (r11, proven) ==============
__global__ __launch_bounds__(256) void sage_gather_kernel(
        const unsigned short* __restrict__ hb, const int* __restrict__ row_ptr,
        const unsigned short* __restrict__ sorted_src, const float* __restrict__ invdeg,
        unsigned short* __restrict__ mean_b, int nNodes)
{
    int node = blockIdx.x * 4 + (threadIdx.x >> 6);
    int lane = threadIdx.x & 63;
    if (node >= nNodes) return;
    const int half = lane >> 5;
    const int fq   = lane & 31;              // feature quad: feats fq*4..+3
    const int beg = row_ptr[node];
    const int end = row_ptr[node + 1];

    float4 s0 = make_float4(0.f, 0.f, 0.f, 0.f);
    float4 s1 = make_float4(0.f, 0.f, 0.f, 0.f);
    int e = beg + half;
    for (; e + 2 < end; e += 4) {
        int sA = sorted_src[e];
        int sB = sorted_src[e + 2];
        ushort4 vA = *(const ushort4*)(hb + (long)sA * DFEAT + fq * 4);
        ushort4 vB = *(const ushort4*)(hb + (long)sB * DFEAT + fq * 4);
        s0.x += bf2f(vA.x); s0.y += bf2f(vA.y); s0.z += bf2f(vA.z); s0.w += bf2f(vA.w);
        s1.x += bf2f(vB.x); s1.y += bf2f(vB.y); s1.z += bf2f(vB.z); s1.w += bf2f(vB.w);
    }
    for (; e < end; e += 2) {
        int sA = sorted_src[e];
        ushort4 vA = *(const ushort4*)(hb + (long)sA * DFEAT + fq * 4);
        s0.x += bf2f(vA.x); s0.y += bf2f(vA.y); s0.z += bf2f(vA.z); s0.w += bf2f(vA.w);
    }
    float sx = s0.x + s1.x, sy = s0.y + s1.y, sz = s0.z + s1.z, sw = s0.w + s1.w;
    sx += __shfl_down(sx, 32);
    sy += __shfl_down(sy, 32);
    sz += __shfl_down(sz, 32);
    sw += __shfl_down(sw, 32);
    if (half == 0) {
        float sc = invdeg[node];
        ushort4 r;
        r.x = f2bf_rtne(sx * sc); r.y = f2bf_rtne(sy * sc);
        r.z = f2bf_rtne(sz * sc); r.w = f2bf_rtne(sw * sc);
        *(ushort4*)(mean_b + (long)node * DFEAT + fq * 4) = r;
    }
}

// ================= all-bf16 MFMA dual-matmul + bias + relu (r11, proven) ========
template<int NT, bool RELU, bool FINAL>
__global__ __launch_bounds__(64) void sage_mm_mfma_kernel(
        const unsigned short* __restrict__ hb_self, const unsigned short* __restrict__ mean_b,
        const unsigned short* __restrict__ Whi, const unsigned short* __restrict__ Wlo,
        const float* __restrict__ bias, float* __restrict__ out,
        unsigned short* __restrict__ hb_out, int M)
{
    constexpr int N = NT * 16;
    const int lane = threadIdx.x;
    const int q    = lane >> 4;
    const int l16  = lane & 15;
    const int rowbase = blockIdx.x * 32;

    floatx4 acc[2][NT];
    #pragma unroll
    for (int mt = 0; mt < 2; mt++)
        #pragma unroll
        for (int nt = 0; nt < NT; nt++)
            acc[mt][nt] = (floatx4){0.f, 0.f, 0.f, 0.f};

    int r0 = rowbase + l16;       if (r0 >= M) r0 = M - 1;
    int r1 = rowbase + 16 + l16;  if (r1 >= M) r1 = M - 1;
    const int rr[2] = {r0, r1};

    #pragma unroll
    for (int kt = 0; kt < 8; kt++) {
        const int koff = (kt & 3) * 32 + q * 8;
        const unsigned short* srcb = (kt < 4) ? hb_self : mean_b;
        short8 am[2];
        #pragma unroll
        for (int mt = 0; mt < 2; mt++)
            am[mt] = *(const short8*)(srcb + (long)rr[mt] * DFEAT + koff);
        #pragma unroll
        for (int nt = 0; nt < NT; nt++) {
            long fb = ((long)(kt * NT + nt) * 64 + lane) * 8;
            short8 bhi = *(const short8*)(Whi + fb);
            short8 blo = *(const short8*)(Wlo + fb);
            #pragma unroll
            for (int mt = 0; mt < 2; mt++) {
                acc[mt][nt] = __builtin_amdgcn_mfma_f32_16x16x32_bf16(am[mt], bhi, acc[mt][nt], 0, 0, 0);
                acc[mt][nt] = __builtin_amdgcn_mfma_f32_16x16x32_bf16(am[mt], blo, acc[mt][nt], 0, 0, 0);
            }
        }
    }

    #pragma unroll
    for (int nt = 0; nt < NT; nt++) {
        float bv = bias[nt * 16 + l16];
        #pragma unroll
        for (int mt = 0; mt < 2; mt++) {
            #pragma unroll
            for (int reg = 0; reg < 4; reg++) {
                int grow = rowbase + mt * 16 + q * 4 + reg;
                if (grow < M) {
                    float v = acc[mt][nt][reg] + bv;
                    if (RELU) v = fmaxf(v, 0.f);
                    long idx = (long)grow * N + nt * 16 + l16;
                    if (FINAL) out[idx] = v;
                    else       hb_out[idx] = f2bf_rtne(v);
                }
            }
        }
    }
}

extern "C" void kernel_launch(void* const* d_in, const int* in_sizes, int n_in,
                              void* d_out, int out_size, void* d_ws, size_t ws_size,
                              hipStream_t stream) {
    const float* x   = (const float*)d_in[0];
    const int*   ei  = (const int*)d_in[1];
    const float* Ws0 = (const float*)d_in[2];
    const float* Wn0 = (const float*)d_in[3];
    const float* b0  = (const float*)d_in[4];
    const float* Ws1 = (const float*)d_in[5];
    const float* Wn1 = (const float*)d_in[6];
    const float* b1  = (const float*)d_in[7];
    const float* Ws2 = (const float*)d_in[8];
    const float* Wn2 = (const float*)d_in[9];
    const float* b2  = (const float*)d_in[10];
    float* out = (float*)d_out;

    const int* src = ei;
    const int* dst = ei + N_EDGES;

    // ---- workspace layout ----
    char* ws = (char*)d_ws;
    float* invdeg     = (float*)ws;   ws += 50176 * 4;
    int*   cnt        = (int*)ws;     ws += 50176 * 4;
    int*   row_ptr    = (int*)ws;     ws += 50432 * 4;
    int*   cursor     = (int*)ws;     ws += 50432 * 4;
    int*   bsum       = (int*)ws;     ws += 256 * 4;
    unsigned* ctrs    = (unsigned*)ws; ws += 256 * 4;
    unsigned short* sorted_src = (unsigned short*)ws; ws += 600064 * 2;
    unsigned short* Whi0 = (unsigned short*)ws; ws += 8 * 8 * 64 * 8 * 2;   // 64 KB
    unsigned short* Wlo0 = (unsigned short*)ws; ws += 8 * 8 * 64 * 8 * 2;
    unsigned short* Whi1 = (unsigned short*)ws; ws += 8 * 8 * 64 * 8 * 2;
    unsigned short* Wlo1 = (unsigned short*)ws; ws += 8 * 8 * 64 * 8 * 2;
    unsigned short* Whi2 = (unsigned short*)ws; ws += 8 * 4 * 64 * 8 * 2;   // 32 KB
    unsigned short* Wlo2 = (unsigned short*)ws; ws += 8 * 4 * 64 * 8 * 2;
    unsigned short* hb_a = (unsigned short*)ws; ws += (long)N_NODES * DFEAT * 2; // 12.8 MB
    unsigned short* hb_b = (unsigned short*)ws; ws += (long)N_NODES * DFEAT * 2; // 12.8 MB
    unsigned short* mean_b = (unsigned short*)ws; ws += (long)N_NODES * DFEAT * 2; // 12.8 MB

    // ---- dispatch 1: prep ----
    sage_prep_kernel<<<1024, 256, 0, stream>>>(
        x, Ws0, Wn0, Ws1, Wn1, Ws2, Wn2,
        Whi0, Wlo0, Whi1, Wlo1, Whi2, Wlo2, hb_a, cnt, ctrs);

    // ---- dispatch 2: CSR build (full-width phases, software barriers) ----
    sage_csr_kernel<<<CSR_NB, 256, 0, stream>>>(
        src, dst, cnt, bsum, row_ptr, cursor, invdeg, sorted_src, ctrs);

    const int gather_blocks = (N_NODES + 3) / 4;   // wave per node
    const int mm_blocks = (N_NODES + 31) / 32;     // 1563 single-wave blocks

    // ---- layer 0 ----
    sage_gather_kernel<<<gather_blocks, 256, 0, stream>>>(
        hb_a, row_ptr, sorted_src, invdeg, mean_b, N_NODES);
    sage_mm_mfma_kernel<8, true, false><<<mm_blocks, 64, 0, stream>>>(
        hb_a, mean_b, Whi0, Wlo0, b0, nullptr, hb_b, N_NODES);

    // ---- layer 1 ----
    sage_gather_kernel<<<gather_blocks, 256, 0, stream>>>(
        hb_b, row_ptr, sorted_src, invdeg, mean_b, N_NODES);
    sage_mm_mfma_kernel<8, true, false><<<mm_blocks, 64, 0, stream>>>(
        hb_b, mean_b, Whi1, Wlo1, b1, nullptr, hb_a, N_NODES);

    // ---- layer 2 ----
    sage_gather_kernel<<<gather_blocks, 256, 0, stream>>>(
        hb_a, row_ptr, sorted_src, invdeg, mean_b, N_NODES);
    sage_mm_mfma_kernel<4, false, true><<<mm_blocks, 64, 0, stream>>>(
        hb_a, mean_b, Whi2, Wlo2, b2, out, nullptr, N_NODES);
}

// Round 14
// 391.415 us; speedup vs baseline: 1.4365x; 1.4365x over previous
//
#include <hip/hip_runtime.h>

#define N_NODES 50000
#define N_EDGES 600000
#define DFEAT   128
#define SCAN_NB 196                      // 196 blocks of 256 counts

typedef __attribute__((ext_vector_type(8))) short short8;
typedef __attribute__((ext_vector_type(4))) float floatx4;

__device__ __forceinline__ unsigned short f2bf_rtne(float f) {
    unsigned b = __float_as_uint(f);
    return (unsigned short)((b + 0x7FFFu + ((b >> 16) & 1u)) >> 16);
}
__device__ __forceinline__ float bf2f(unsigned short u) {
    return __uint_as_float(((unsigned)u) << 16);
}

// ================= prep: zero cnt/ctrs | x->bf16 table | W split/swizzle =========
__global__ __launch_bounds__(256) void sage_prep_kernel(
        const float* __restrict__ x,
        const float* __restrict__ Ws0, const float* __restrict__ Wn0,
        const float* __restrict__ Ws1, const float* __restrict__ Wn1,
        const float* __restrict__ Ws2, const float* __restrict__ Wn2,
        unsigned short* __restrict__ Whi0, unsigned short* __restrict__ Wlo0,
        unsigned short* __restrict__ Whi1, unsigned short* __restrict__ Wlo1,
        unsigned short* __restrict__ Whi2, unsigned short* __restrict__ Wlo2,
        unsigned short* __restrict__ hb, int* __restrict__ cnt,
        unsigned* __restrict__ ctrs)
{
    const int gtid = blockIdx.x * 256 + threadIdx.x;
    const int gsz  = gridDim.x * 256;
    if (gtid < 8) ctrs[gtid] = 0u;
    for (int i = gtid; i < 50176; i += gsz) cnt[i] = 0;
    for (int i = gtid; i < N_NODES * DFEAT / 4; i += gsz) {
        float4 v = ((const float4*)x)[i];
        ushort4 o;
        o.x = f2bf_rtne(v.x); o.y = f2bf_rtne(v.y);
        o.z = f2bf_rtne(v.z); o.w = f2bf_rtne(v.w);
        ((ushort4*)hb)[i] = o;
    }
    for (int it = gtid; it < 160 * 64; it += gsz) {
        int fid_g = it >> 6;
        int lane  = it & 63;
        const float *Ws, *Wn;
        unsigned short *Whi, *Wlo;
        int N, fid;
        if (fid_g < 64)       { Ws = Ws0; Wn = Wn0; Whi = Whi0; Wlo = Wlo0; N = 128; fid = fid_g; }
        else if (fid_g < 128) { Ws = Ws1; Wn = Wn1; Whi = Whi1; Wlo = Wlo1; N = 128; fid = fid_g - 64; }
        else                  { Ws = Ws2; Wn = Wn2; Whi = Whi2; Wlo = Wlo2; N = 64;  fid = fid_g - 128; }
        int NT = N / 16;
        int kt = fid / NT, nt = fid % NT;
        int kbase = kt * 32 + (lane >> 4) * 8;
        int n = nt * 16 + (lane & 15);
        long base = ((long)fid * 64 + lane) * 8;
        #pragma unroll
        for (int j = 0; j < 8; j++) {
            int k = kbase + j;
            float w = (k < 128) ? Ws[k * N + n] : Wn[(k - 128) * N + n];
            unsigned bb = __float_as_uint(w);
            unsigned hib = bb & 0xFFFF0000u;
            float lo = w - __uint_as_float(hib);
            Whi[base + j] = (unsigned short)(bb >> 16);
            Wlo[base + j] = (unsigned short)(__float_as_uint(lo) >> 16);
        }
    }
}

// ================= histogram of dst =================
__global__ void sage_hist_kernel(const int* __restrict__ dst, int* __restrict__ cnt, int nE) {
    int e = blockIdx.x * blockDim.x + threadIdx.x;
    if (e < nE) atomicAdd(&cnt[dst[e]], 1);
}

// ===== merged scan: local scan + ticket-scan of block totals + emit ============
// 196 blocks only — the scale at which the ticket-spin was proven cheap (r12).
__global__ __launch_bounds__(256) void sage_scan_kernel(
        const int* __restrict__ cnt, int* __restrict__ bsum, int* __restrict__ bexcl,
        int* __restrict__ row_ptr, int* __restrict__ cursor,
        float* __restrict__ invdeg, unsigned* __restrict__ ctrs)
{
    const int t = threadIdx.x;
    const int b = blockIdx.x;
    const int i = b * 256 + t;
    const int lane = t & 63, wid = t >> 6;

    __shared__ int sws[4];
    __shared__ int lastflag;

    int v = (i < N_NODES) ? cnt[i] : 0;
    int incl = v;
    #pragma unroll
    for (int off = 1; off < 64; off <<= 1) {
        int y = __shfl_up(incl, off);
        if (lane >= off) incl += y;
    }
    if (lane == 63) sws[wid] = incl;
    __syncthreads();
    int wpre = 0;
    for (int w = 0; w < wid; w++) wpre += sws[w];
    int lincl = wpre + incl;                 // block-inclusive prefix
    int btot  = sws[0] + sws[1] + sws[2] + sws[3];

    if (t == 0) {
        bsum[b] = btot;
        __threadfence();
        unsigned old = __hip_atomic_fetch_add(&ctrs[0], 1u, __ATOMIC_ACQ_REL,
                                              __HIP_MEMORY_SCOPE_AGENT);
        lastflag = (old == (unsigned)(SCAN_NB - 1)) ? 1 : 0;
    }
    __syncthreads();
    if (lastflag) {     // last-arriving block exclusive-scans the 196 totals
        __shared__ int sw2[4];
        int v2 = (t < SCAN_NB) ? bsum[t] : 0;
        int incl2 = v2;
        #pragma unroll
        for (int off = 1; off < 64; off <<= 1) {
            int y = __shfl_up(incl2, off);
            if (lane >= off) incl2 += y;
        }
        if (lane == 63) sw2[wid] = incl2;
        __syncthreads();
        int wpre2 = 0;
        for (int w = 0; w < wid; w++) wpre2 += sw2[w];
        if (t < SCAN_NB) bexcl[t] = wpre2 + incl2 - v2;   // exclusive
        __syncthreads();
        if (t == 0) {
            __threadfence();
            __hip_atomic_store(&ctrs[1], 1u, __ATOMIC_RELEASE,
                               __HIP_MEMORY_SCOPE_AGENT);
        }
    } else if (t == 0) {
        while (__hip_atomic_load(&ctrs[1], __ATOMIC_ACQUIRE,
                                 __HIP_MEMORY_SCOPE_AGENT) == 0u)
            __builtin_amdgcn_s_sleep(2);
        __threadfence();
    }
    __syncthreads();

    int excl = bexcl[b] + lincl - v;
    if (i < N_NODES) {
        row_ptr[i] = excl;
        cursor[i]  = excl;
        invdeg[i]  = 1.0f / fmaxf((float)v, 1.0f);
    }
    if (i == N_NODES - 1) row_ptr[N_NODES] = excl + v;
}

// ================= fill sorted_src (ushort) via cursor =================
__global__ void sage_fill_kernel(const int* __restrict__ src, const int* __restrict__ dst,
                                 int* __restrict__ cursor,
                                 unsigned short* __restrict__ sorted_src, int nE) {
    int e = blockIdx.x * blockDim.x + threadIdx.x;
    if (e < nE) {
        int p = atomicAdd(&cursor[dst[e]], 1);
        sorted_src[p] = (unsigned short)src[e];
    }
}

// ================= two-pass feature-halved gather =================
// Blocks < 12500 do features 0..63, the rest 64..127. In-order dispatch keeps
// the halves temporally separate -> random working set 6.4 MB/pass (vs 12.8).
// Per edge: one fully-consumed 128B line (32 lanes x ushort2). Per-feature
// accumulation order identical to r11 -> bit-identical result.
__global__ __launch_bounds__(256) void sage_gather_kernel(
        const unsigned short* __restrict__ hb, const int* __restrict__ row_ptr,
        const unsigned short* __restrict__ sorted_src, const float* __restrict__ invdeg,
        unsigned short* __restrict__ mean_b, int nNodes)
{
    const int nodeBlocks = (N_NODES + 3) / 4;     // 12500
    const int fhalf = (blockIdx.x >= nodeBlocks) ? 1 : 0;
    const int nb = blockIdx.x - fhalf * nodeBlocks;
    int node = nb * 4 + (threadIdx.x >> 6);
    int lane = threadIdx.x & 63;
    if (node >= nNodes) return;
    const int ehalf = lane >> 5;                  // edge parity
    const int fq    = lane & 31;                  // feature pair within half
    const int beg = row_ptr[node];
    const int end = row_ptr[node + 1];
    const unsigned short* tab = hb + fhalf * 64 + fq * 2;

    float2 s0 = make_float2(0.f, 0.f);
    float2 s1 = make_float2(0.f, 0.f);
    int e = beg + ehalf;
    for (; e + 2 < end; e += 4) {
        int sA = sorted_src[e];
        int sB = sorted_src[e + 2];
        ushort2 vA = *(const ushort2*)(tab + (long)sA * DFEAT);
        ushort2 vB = *(const ushort2*)(tab + (long)sB * DFEAT);
        s0.x += bf2f(vA.x); s0.y += bf2f(vA.y);
        s1.x += bf2f(vB.x); s1.y += bf2f(vB.y);
    }
    for (; e < end; e += 2) {
        int sA = sorted_src[e];
        ushort2 vA = *(const ushort2*)(tab + (long)sA * DFEAT);
        s0.x += bf2f(vA.x); s0.y += bf2f(vA.y);
    }
    float sx = s0.x + s1.x, sy = s0.y + s1.y;
    sx += __shfl_down(sx, 32);
    sy += __shfl_down(sy, 32);
    if (ehalf == 0) {
        float sc = invdeg[node];
        ushort2 r;
        r.x = f2bf_rtne(sx * sc);
        r.y = f2bf_rtne(sy * sc);
        *(ushort2*)(mean_b + (long)node * DFEAT + fhalf * 64 + fq * 2) = r;
    }
}

// ================= all-bf16 MFMA dual-matmul + bias + relu (r11, proven) ========
template<int NT, bool RELU, bool FINAL>
__global__ __launch_bounds__(64) void sage_mm_mfma_kernel(
        const unsigned short* __restrict__ hb_self, const unsigned short* __restrict__ mean_b,
        const unsigned short* __restrict__ Whi, const unsigned short* __restrict__ Wlo,
        const float* __restrict__ bias, float* __restrict__ out,
        unsigned short* __restrict__ hb_out, int M)
{
    constexpr int N = NT * 16;
    const int lane = threadIdx.x;
    const int q    = lane >> 4;
    const int l16  = lane & 15;
    const int rowbase = blockIdx.x * 32;

    floatx4 acc[2][NT];
    #pragma unroll
    for (int mt = 0; mt < 2; mt++)
        #pragma unroll
        for (int nt = 0; nt < NT; nt++)
            acc[mt][nt] = (floatx4){0.f, 0.f, 0.f, 0.f};

    int r0 = rowbase + l16;       if (r0 >= M) r0 = M - 1;
    int r1 = rowbase + 16 + l16;  if (r1 >= M) r1 = M - 1;
    const int rr[2] = {r0, r1};

    #pragma unroll
    for (int kt = 0; kt < 8; kt++) {
        const int koff = (kt & 3) * 32 + q * 8;
        const unsigned short* srcb = (kt < 4) ? hb_self : mean_b;
        short8 am[2];
        #pragma unroll
        for (int mt = 0; mt < 2; mt++)
            am[mt] = *(const short8*)(srcb + (long)rr[mt] * DFEAT + koff);
        #pragma unroll
        for (int nt = 0; nt < NT; nt++) {
            long fb = ((long)(kt * NT + nt) * 64 + lane) * 8;
            short8 bhi = *(const short8*)(Whi + fb);
            short8 blo = *(const short8*)(Wlo + fb);
            #pragma unroll
            for (int mt = 0; mt < 2; mt++) {
                acc[mt][nt] = __builtin_amdgcn_mfma_f32_16x16x32_bf16(am[mt], bhi, acc[mt][nt], 0, 0, 0);
                acc[mt][nt] = __builtin_amdgcn_mfma_f32_16x16x32_bf16(am[mt], blo, acc[mt][nt], 0, 0, 0);
            }
        }
    }

    #pragma unroll
    for (int nt = 0; nt < NT; nt++) {
        float bv = bias[nt * 16 + l16];
        #pragma unroll
        for (int mt = 0; mt < 2; mt++) {
            #pragma unroll
            for (int reg = 0; reg < 4; reg++) {
                int grow = rowbase + mt * 16 + q * 4 + reg;
                if (grow < M) {
                    float v = acc[mt][nt][reg] + bv;
                    if (RELU) v = fmaxf(v, 0.f);
                    long idx = (long)grow * N + nt * 16 + l16;
                    if (FINAL) out[idx] = v;
                    else       hb_out[idx] = f2bf_rtne(v);
                }
            }
        }
    }
}

extern "C" void kernel_launch(void* const* d_in, const int* in_sizes, int n_in,
                              void* d_out, int out_size, void* d_ws, size_t ws_size,
                              hipStream_t stream) {
    const float* x   = (const float*)d_in[0];
    const int*   ei  = (const int*)d_in[1];
    const float* Ws0 = (const float*)d_in[2];
    const float* Wn0 = (const float*)d_in[3];
    const float* b0  = (const float*)d_in[4];
    const float* Ws1 = (const float*)d_in[5];
    const float* Wn1 = (const float*)d_in[6];
    const float* b1  = (const float*)d_in[7];
    const float* Ws2 = (const float*)d_in[8];
    const float* Wn2 = (const float*)d_in[9];
    const float* b2  = (const float*)d_in[10];
    float* out = (float*)d_out;

    const int* src = ei;
    const int* dst = ei + N_EDGES;

    // ---- workspace layout ----
    char* ws = (char*)d_ws;
    float* invdeg     = (float*)ws;   ws += 50176 * 4;
    int*   cnt        = (int*)ws;     ws += 50176 * 4;
    int*   row_ptr    = (int*)ws;     ws += 50432 * 4;
    int*   cursor     = (int*)ws;     ws += 50432 * 4;
    int*   bsum       = (int*)ws;     ws += 256 * 4;
    int*   bexcl      = (int*)ws;     ws += 256 * 4;
    unsigned* ctrs    = (unsigned*)ws; ws += 256 * 4;
    unsigned short* sorted_src = (unsigned short*)ws; ws += 600064 * 2;
    unsigned short* Whi0 = (unsigned short*)ws; ws += 8 * 8 * 64 * 8 * 2;   // 64 KB
    unsigned short* Wlo0 = (unsigned short*)ws; ws += 8 * 8 * 64 * 8 * 2;
    unsigned short* Whi1 = (unsigned short*)ws; ws += 8 * 8 * 64 * 8 * 2;
    unsigned short* Wlo1 = (unsigned short*)ws; ws += 8 * 8 * 64 * 8 * 2;
    unsigned short* Whi2 = (unsigned short*)ws; ws += 8 * 4 * 64 * 8 * 2;   // 32 KB
    unsigned short* Wlo2 = (unsigned short*)ws; ws += 8 * 4 * 64 * 8 * 2;
    unsigned short* hb_a = (unsigned short*)ws; ws += (long)N_NODES * DFEAT * 2; // 12.8 MB
    unsigned short* hb_b = (unsigned short*)ws; ws += (long)N_NODES * DFEAT * 2; // 12.8 MB
    unsigned short* mean_b = (unsigned short*)ws; ws += (long)N_NODES * DFEAT * 2; // 12.8 MB

    // ---- build chain (4 dispatches) ----
    sage_prep_kernel<<<1024, 256, 0, stream>>>(
        x, Ws0, Wn0, Ws1, Wn1, Ws2, Wn2,
        Whi0, Wlo0, Whi1, Wlo1, Whi2, Wlo2, hb_a, cnt, ctrs);
    sage_hist_kernel<<<(N_EDGES + 255) / 256, 256, 0, stream>>>(dst, cnt, N_EDGES);
    sage_scan_kernel<<<SCAN_NB, 256, 0, stream>>>(
        cnt, bsum, bexcl, row_ptr, cursor, invdeg, ctrs);
    sage_fill_kernel<<<(N_EDGES + 255) / 256, 256, 0, stream>>>(
        src, dst, cursor, sorted_src, N_EDGES);

    const int gather_blocks = 2 * ((N_NODES + 3) / 4);   // 25000 (two passes)
    const int mm_blocks = (N_NODES + 31) / 32;           // 1563 single-wave blocks

    // ---- layer 0 ----
    sage_gather_kernel<<<gather_blocks, 256, 0, stream>>>(
        hb_a, row_ptr, sorted_src, invdeg, mean_b, N_NODES);
    sage_mm_mfma_kernel<8, true, false><<<mm_blocks, 64, 0, stream>>>(
        hb_a, mean_b, Whi0, Wlo0, b0, nullptr, hb_b, N_NODES);

    // ---- layer 1 ----
    sage_gather_kernel<<<gather_blocks, 256, 0, stream>>>(
        hb_b, row_ptr, sorted_src, invdeg, mean_b, N_NODES);
    sage_mm_mfma_kernel<8, true, false><<<mm_blocks, 64, 0, stream>>>(
        hb_b, mean_b, Whi1, Wlo1, b1, nullptr, hb_a, N_NODES);

    // ---- layer 2 ----
    sage_gather_kernel<<<gather_blocks, 256, 0, stream>>>(
        hb_a, row_ptr, sorted_src, invdeg, mean_b, N_NODES);
    sage_mm_mfma_kernel<4, false, true><<<mm_blocks, 64, 0, stream>>>(
        hb_a, mean_b, Whi2, Wlo2, b2, out, nullptr, N_NODES);
}